// Round 1
// baseline (2337.255 us; speedup 1.0000x reference)
//
#include <hip/hip_runtime.h>
#include <hip/hip_bf16.h>
#include <stdint.h>

// ---------------- constants ----------------
#define M_TOK 4096      // TWO_B*SEQ = 8*512
#define NV    32000     // vocab
#define KH    4096      // hidden
#define BM    128
#define BN    128
#define BK    64
#define NBLK  (NV / BN)     // 250
#define MBLK  (M_TOK / BM)  // 32
#define IGNORE_INDEX (-100)

typedef __bf16 bf16;
typedef bf16  bf16x8 __attribute__((ext_vector_type(8)));
typedef bf16  bf16x4 __attribute__((ext_vector_type(4)));
typedef float f32x4  __attribute__((ext_vector_type(4)));

__device__ __forceinline__ void async_copy16(const void* g, void* l) {
    __builtin_amdgcn_global_load_lds(
        (const __attribute__((address_space(1))) void*)g,
        (__attribute__((address_space(3))) void*)l, 16, 0, 0);
}

// ---------------- fp32 -> bf16 convert (input activations) ----------------
__global__ __launch_bounds__(256) void cvt_bf16_kernel(const float* __restrict__ src,
                                                       bf16* __restrict__ dst, int n4) {
    int i = blockIdx.x * blockDim.x + threadIdx.x;
    int stride = gridDim.x * blockDim.x;
    const float4* s4 = (const float4*)src;
    bf16x4* d4 = (bf16x4*)dst;
    for (; i < n4; i += stride) {
        float4 v = s4[i];
        bf16x4 o;
        o[0] = (bf16)v.x; o[1] = (bf16)v.y; o[2] = (bf16)v.z; o[3] = (bf16)v.w;
        d4[i] = o;
    }
}

// ---------------- target logit: full fp32 dot per token ----------------
// one wave per token, 4 tokens per 256-thread block
__global__ __launch_bounds__(256) void tlogit_kernel(const float* __restrict__ inp,
                                                     const float* __restrict__ W,
                                                     const float* __restrict__ bias,
                                                     const int* __restrict__ target,
                                                     float* __restrict__ tlogit) {
    const int wave = threadIdx.x >> 6, lane = threadIdx.x & 63;
    const int t = blockIdx.x * 4 + wave;
    if (t >= M_TOK) return;
    int tg = target[t];
    int row = (tg == IGNORE_INDEX) ? 0 : tg;
    const float4* a4 = (const float4*)(inp + (long)t * KH);
    const float4* w4 = (const float4*)(W + (long)row * KH);
    float acc = 0.f;
#pragma unroll
    for (int i = 0; i < 16; i++) {
        float4 a = a4[i * 64 + lane];
        float4 w = w4[i * 64 + lane];
        acc += a.x * w.x + a.y * w.y + a.z * w.z + a.w * w.w;
    }
#pragma unroll
    for (int d = 1; d < 64; d <<= 1) acc += __shfl_xor(acc, d, 64);
    if (lane == 0) tlogit[t] = acc + bias[row];
}

// ---------------- fused GEMM + per-tile (max, sumexp) ----------------
// A: [M_TOK][KH] bf16 (row-major), W: [NV][KH] fp32 (row-major, converted on the fly)
// Each block: 128 tokens x 128 vocab, full K. Epilogue reduces its 128 cols to
// per-token partial (max, sumexp) -> pm/ps [NBLK][M_TOK].
__global__ __launch_bounds__(256) void gemm_lse_kernel(const bf16* __restrict__ A,
                                                       const float* __restrict__ W,
                                                       const float* __restrict__ bias,
                                                       float* __restrict__ pm,
                                                       float* __restrict__ ps) {
    const int tid = threadIdx.x;
    const int wave = tid >> 6, lane = tid & 63;
    const int wm = wave & 1, wn = wave >> 1;
    const int bx = blockIdx.x;
    const int mblk = bx & 31;   // fast dim: 32 M tiles share the same W tile
    const int nblk = bx >> 5;   // 250 N tiles
    const int m0 = mblk * BM, n0 = nblk * BN;

    __shared__ bf16 sA[BM * BK];
    __shared__ bf16 sB[BN * BK];
    __shared__ float red_m[2][BM];
    __shared__ float red_s[2][BM];

    f32x4 acc[4][4] = {};

    const int srow = tid >> 3;          // 0..31
    const int scol = (tid & 7) * 8;     // 0..56
    const bf16*  aptr = A + (long)(m0 + srow) * KH + scol;
    const float* wptr = W + (long)(n0 + srow) * KH + scol;
    bf16* sA_dst = sA + tid * 8;

    for (int k0 = 0; k0 < KH; k0 += BK) {
        // stage A (bf16) via async global->LDS, 16B per lane, 4 chunks of 32 rows
#pragma unroll
        for (int i = 0; i < 4; i++) {
            async_copy16(aptr + (long)i * 32 * KH + k0, sA_dst + i * 256 * 8);
        }
        // stage W (fp32 -> bf16) through VGPRs
#pragma unroll
        for (int i = 0; i < 4; i++) {
            const float* wp = wptr + (long)i * 32 * KH + k0;
            float4 w0 = *(const float4*)(wp);
            float4 w1 = *(const float4*)(wp + 4);
            bf16x8 b;
            b[0] = (bf16)w0.x; b[1] = (bf16)w0.y; b[2] = (bf16)w0.z; b[3] = (bf16)w0.w;
            b[4] = (bf16)w1.x; b[5] = (bf16)w1.y; b[6] = (bf16)w1.z; b[7] = (bf16)w1.w;
            *(bf16x8*)(sB + (i * 256 + tid) * 8) = b;
        }
        __syncthreads();
        // compute: 2 k-steps of 32, 4x4 MFMA tiles per wave
#pragma unroll
        for (int kk = 0; kk < BK; kk += 32) {
            bf16x8 af[4], bfr[4];
            const int rbase = wm * 64 + (lane & 15);
            const int cbase = wn * 64 + (lane & 15);
            const int koff = kk + (lane >> 4) * 8;
#pragma unroll
            for (int t = 0; t < 4; t++)
                af[t] = *(const bf16x8*)(sA + (rbase + t * 16) * BK + koff);
#pragma unroll
            for (int t = 0; t < 4; t++)
                bfr[t] = *(const bf16x8*)(sB + (cbase + t * 16) * BK + koff);
#pragma unroll
            for (int mt = 0; mt < 4; mt++)
#pragma unroll
                for (int nt = 0; nt < 4; nt++)
                    acc[mt][nt] = __builtin_amdgcn_mfma_f32_16x16x32_bf16(
                        af[mt], bfr[nt], acc[mt][nt], 0, 0, 0);
        }
        __syncthreads();
    }

    // ---- epilogue: bias add + per-row (max, sumexp) over this block's 128 cols ----
    float bv[4];
#pragma unroll
    for (int nt = 0; nt < 4; nt++)
        bv[nt] = bias[n0 + wn * 64 + nt * 16 + (lane & 15)];

#pragma unroll
    for (int mt = 0; mt < 4; mt++) {
        float rm[4], rs[4];
#pragma unroll
        for (int r = 0; r < 4; r++) {
            float v0 = acc[mt][0][r] + bv[0];
            float v1 = acc[mt][1][r] + bv[1];
            float v2 = acc[mt][2][r] + bv[2];
            float v3 = acc[mt][3][r] + bv[3];
            float mx = fmaxf(fmaxf(v0, v1), fmaxf(v2, v3));
#pragma unroll
            for (int d = 1; d < 16; d <<= 1) mx = fmaxf(mx, __shfl_xor(mx, d, 64));
            float s = __expf(v0 - mx) + __expf(v1 - mx) + __expf(v2 - mx) + __expf(v3 - mx);
#pragma unroll
            for (int d = 1; d < 16; d <<= 1) s += __shfl_xor(s, d, 64);
            rm[r] = mx; rs[r] = s;
        }
        if ((lane & 15) == 0) {
            int rl = wm * 64 + mt * 16 + (lane >> 4) * 4;
#pragma unroll
            for (int r = 0; r < 4; r++) {
                red_m[wn][rl + r] = rm[r];
                red_s[wn][rl + r] = rs[r];
            }
        }
    }
    __syncthreads();
    if (tid < BM) {
        float m0v = red_m[0][tid], s0v = red_s[0][tid];
        float m1v = red_m[1][tid], s1v = red_s[1][tid];
        float mm = fmaxf(m0v, m1v);
        float ss = s0v * __expf(m0v - mm) + s1v * __expf(m1v - mm);
        long idx = (long)nblk * M_TOK + m0 + tid;
        pm[idx] = mm;
        ps[idx] = ss;
    }
}

// ---------------- combine partials -> per-token logp ----------------
__global__ __launch_bounds__(256) void lse_combine_kernel(const float* __restrict__ pm,
                                                          const float* __restrict__ ps,
                                                          const float* __restrict__ tlogit,
                                                          const int* __restrict__ target,
                                                          float* __restrict__ per_tok) {
    int t = blockIdx.x * blockDim.x + threadIdx.x;
    if (t >= M_TOK) return;
    float m = -1e30f, s = 0.f;
    for (int j = 0; j < NBLK; j++) {
        float mj = pm[j * M_TOK + t];
        float sj = ps[j * M_TOK + t];
        if (mj > m) {
            s = s * expf(m - mj) + sj;
            m = mj;
        } else {
            s += sj * expf(mj - m);
        }
    }
    float lse = m + logf(s);
    int tg = target[t];
    per_tok[t] = (tg != IGNORE_INDEX) ? (tlogit[t] - lse) : 0.0f;
}

// ---------------- final scalar loss ----------------
// 8 waves, one per sequence of 512 tokens
__global__ __launch_bounds__(512) void final_kernel(const float* __restrict__ per_tok,
                                                    const int* __restrict__ target,
                                                    const float* __restrict__ refc,
                                                    const float* __restrict__ refr,
                                                    float* __restrict__ out) {
    __shared__ float ssum[8];
    __shared__ float scnt[8];
    const int w = threadIdx.x >> 6, lane = threadIdx.x & 63;
    float sum = 0.f, cnt = 0.f;
#pragma unroll
    for (int i = 0; i < 8; i++) {
        int t = w * 512 + i * 64 + lane;
        sum += per_tok[t];
        cnt += (target[t] != IGNORE_INDEX) ? 1.f : 0.f;
    }
#pragma unroll
    for (int d = 1; d < 64; d <<= 1) {
        sum += __shfl_xor(sum, d, 64);
        cnt += __shfl_xor(cnt, d, 64);
    }
    if (lane == 0) { ssum[w] = sum; scnt[w] = cnt; }
    __syncthreads();
    if (threadIdx.x == 0) {
        float avg[8];
#pragma unroll
        for (int i = 0; i < 8; i++) avg[i] = ssum[i] / scnt[i];
        float nll_num = 0.f, nll_den = 0.f;
#pragma unroll
        for (int i = 0; i < 4; i++) { nll_num += ssum[i]; nll_den += scnt[i]; }
        float nll = -nll_num / nll_den;
        float pref = 0.f;
#pragma unroll
        for (int i = 0; i < 4; i++) {
            float x = 0.1f * ((avg[i] - refc[i]) - (avg[i + 4] - refr[i]));
            // log_sigmoid(x), numerically stable
            float ls = (x >= 0.f) ? -log1pf(expf(-x)) : (x - log1pf(expf(x)));
            pref += -ls;
        }
        pref *= 0.25f;
        out[0] = pref + nll;
    }
}

// ---------------- launch ----------------
extern "C" void kernel_launch(void* const* d_in, const int* in_sizes, int n_in,
                              void* d_out, int out_size, void* d_ws, size_t ws_size,
                              hipStream_t stream) {
    const float* W    = (const float*)d_in[0];  // [32000][4096]
    const float* inp  = (const float*)d_in[1];  // [8][512][4096]
    const int*   tgt  = (const int*)d_in[2];    // [8][512]
    const float* refc = (const float*)d_in[3];  // [4]
    const float* refr = (const float*)d_in[4];  // [4]
    const float* bias = (const float*)d_in[5];  // [32000]
    float* out = (float*)d_out;

    char* ws = (char*)d_ws;
    size_t off = 0;
    bf16* A16 = (bf16*)(ws + off); off += (size_t)M_TOK * KH * sizeof(bf16);   // 32 MB
    float* pm = (float*)(ws + off); off += (size_t)NBLK * M_TOK * sizeof(float); // 4 MB
    float* ps = (float*)(ws + off); off += (size_t)NBLK * M_TOK * sizeof(float); // 4 MB
    float* tl = (float*)(ws + off); off += (size_t)M_TOK * sizeof(float);
    float* ptk = (float*)(ws + off); off += (size_t)M_TOK * sizeof(float);

    cvt_bf16_kernel<<<4096, 256, 0, stream>>>(inp, A16, (M_TOK * KH) / 4);
    tlogit_kernel<<<M_TOK / 4, 256, 0, stream>>>(inp, W, bias, tgt, tl);
    gemm_lse_kernel<<<MBLK * NBLK, 256, 0, stream>>>(A16, W, bias, pm, ps);
    lse_combine_kernel<<<(M_TOK + 255) / 256, 256, 0, stream>>>(pm, ps, tl, tgt, ptk);
    final_kernel<<<1, 512, 0, stream>>>(ptk, tgt, refc, refr, out);
}

// Round 2
// 2105.599 us; speedup vs baseline: 1.1100x; 1.1100x over previous
//
#include <hip/hip_runtime.h>
#include <hip/hip_bf16.h>
#include <stdint.h>

// ---------------- constants ----------------
#define M_TOK 4096      // TWO_B*SEQ = 8*512
#define NV    32000     // vocab
#define KH    4096      // hidden
#define BM    128
#define BN    128
#define BK    64
#define NBLK  (NV / BN)     // 250
#define MBLK  (M_TOK / BM)  // 32
#define IGNORE_INDEX (-100)

typedef __bf16 bf16;
typedef bf16  bf16x8 __attribute__((ext_vector_type(8)));
typedef bf16  bf16x4 __attribute__((ext_vector_type(4)));
typedef float f32x4  __attribute__((ext_vector_type(4)));

__device__ __forceinline__ void async_copy16(const void* g, void* l) {
    __builtin_amdgcn_global_load_lds(
        (const __attribute__((address_space(1))) void*)g,
        (__attribute__((address_space(3))) void*)l, 16, 0, 0);
}

// ---------------- fp32 -> bf16 convert ----------------
__global__ __launch_bounds__(256) void cvt_bf16_kernel(const float* __restrict__ src,
                                                       bf16* __restrict__ dst, int n4) {
    int i = blockIdx.x * blockDim.x + threadIdx.x;
    int stride = gridDim.x * blockDim.x;
    const float4* s4 = (const float4*)src;
    bf16x4* d4 = (bf16x4*)dst;
    for (; i < n4; i += stride) {
        float4 v = s4[i];
        bf16x4 o;
        o[0] = (bf16)v.x; o[1] = (bf16)v.y; o[2] = (bf16)v.z; o[3] = (bf16)v.w;
        d4[i] = o;
    }
}

// ---------------- target logit: full fp32 dot per token ----------------
__global__ __launch_bounds__(256) void tlogit_kernel(const float* __restrict__ inp,
                                                     const float* __restrict__ W,
                                                     const float* __restrict__ bias,
                                                     const int* __restrict__ target,
                                                     float* __restrict__ tlogit) {
    const int wave = threadIdx.x >> 6, lane = threadIdx.x & 63;
    const int t = blockIdx.x * 4 + wave;
    if (t >= M_TOK) return;
    int tg = target[t];
    int row = (tg == IGNORE_INDEX) ? 0 : tg;
    const float4* a4 = (const float4*)(inp + (long)t * KH);
    const float4* w4 = (const float4*)(W + (long)row * KH);
    float acc = 0.f;
#pragma unroll
    for (int i = 0; i < 16; i++) {
        float4 a = a4[i * 64 + lane];
        float4 w = w4[i * 64 + lane];
        acc += a.x * w.x + a.y * w.y + a.z * w.z + a.w * w.w;
    }
#pragma unroll
    for (int d = 1; d < 64; d <<= 1) acc += __shfl_xor(acc, d, 64);
    if (lane == 0) tlogit[t] = acc + bias[row];
}

// ---------------- fused GEMM + per-tile (max, sumexp) ----------------
// LDS layout is XOR-swizzled: row r's 16B chunk c lives at slot (c ^ (r&7)).
// The global_load_lds dst is pinned to base+lane*16, so the swizzle is applied
// by permuting which global chunk each lane fetches (stays within one 128B
// cache line -> still fully coalesced).
template<bool PRECONV>
__global__ __launch_bounds__(256) void gemm_lse_kernel(const bf16* __restrict__ A,
                                                       const void* __restrict__ Wv,
                                                       const float* __restrict__ bias,
                                                       float* __restrict__ pm,
                                                       float* __restrict__ ps) {
    const int tid = threadIdx.x;
    const int wave = tid >> 6, lane = tid & 63;
    const int wm = wave & 1, wn = wave >> 1;
    const int bx = blockIdx.x;
    const int mblk = bx & 31;   // fast dim: 32 M tiles share the same W tile
    const int nblk = bx >> 5;   // 250 N tiles
    const int m0 = mblk * BM, n0 = nblk * BN;

    __shared__ bf16 sA[BM * BK];
    __shared__ bf16 sB[BN * BK];
    __shared__ float red_m[2][BM];
    __shared__ float red_s[2][BM];

    f32x4 acc[4][4] = {};

    const int srow  = tid >> 3;                 // 0..31
    const int slot  = tid & 7;                  // lds 16B slot within row
    const int chunk = slot ^ (srow & 7);        // global 16B chunk to fetch
    const bf16* aptr = A + (long)(m0 + srow) * KH + chunk * 8;
    bf16* sA_dst = sA + tid * 8;
    bf16* sB_dst = sB + tid * 8;

    const bf16*  Wb = (const bf16*)Wv;
    const float* Wf = (const float*)Wv;
    const bf16*  bptr16 = Wb + (long)(n0 + srow) * KH + chunk * 8;
    const float* bptr32 = Wf + (long)(n0 + srow) * KH + chunk * 8;

    for (int k0 = 0; k0 < KH; k0 += BK) {
        // stage A (bf16) async, 4 chunks of 32 rows
#pragma unroll
        for (int i = 0; i < 4; i++)
            async_copy16(aptr + (long)i * 32 * KH + k0, sA_dst + i * 2048);
        if (PRECONV) {
#pragma unroll
            for (int i = 0; i < 4; i++)
                async_copy16(bptr16 + (long)i * 32 * KH + k0, sB_dst + i * 2048);
        } else {
#pragma unroll
            for (int i = 0; i < 4; i++) {
                const float* wp = bptr32 + (long)i * 32 * KH + k0;
                float4 w0 = *(const float4*)(wp);
                float4 w1 = *(const float4*)(wp + 4);
                bf16x8 b;
                b[0] = (bf16)w0.x; b[1] = (bf16)w0.y; b[2] = (bf16)w0.z; b[3] = (bf16)w0.w;
                b[4] = (bf16)w1.x; b[5] = (bf16)w1.y; b[6] = (bf16)w1.z; b[7] = (bf16)w1.w;
                *(bf16x8*)(sB + (i * 32 + srow) * BK + slot * 8) = b;
            }
        }
        __syncthreads();
#pragma unroll
        for (int kk = 0; kk < BK; kk += 32) {
            bf16x8 af[4], bfr[4];
            const int rbase = wm * 64 + (lane & 15);
            const int cbase = wn * 64 + (lane & 15);
            const int c = (kk >> 3) + (lane >> 4);          // chunk idx 0..7
            const int xoff = ((c ^ (lane & 7)) << 3);       // swizzled elem offset
#pragma unroll
            for (int t = 0; t < 4; t++)
                af[t] = *(const bf16x8*)(sA + (rbase + t * 16) * BK + xoff);
#pragma unroll
            for (int t = 0; t < 4; t++)
                bfr[t] = *(const bf16x8*)(sB + (cbase + t * 16) * BK + xoff);
#pragma unroll
            for (int mt = 0; mt < 4; mt++)
#pragma unroll
                for (int nt = 0; nt < 4; nt++)
                    acc[mt][nt] = __builtin_amdgcn_mfma_f32_16x16x32_bf16(
                        af[mt], bfr[nt], acc[mt][nt], 0, 0, 0);
        }
        __syncthreads();
    }

    // ---- epilogue: bias add + per-row (max, sumexp) over this block's 128 cols ----
    float bv[4];
#pragma unroll
    for (int nt = 0; nt < 4; nt++)
        bv[nt] = bias[n0 + wn * 64 + nt * 16 + (lane & 15)];

#pragma unroll
    for (int mt = 0; mt < 4; mt++) {
        float rm[4], rs[4];
#pragma unroll
        for (int r = 0; r < 4; r++) {
            float v0 = acc[mt][0][r] + bv[0];
            float v1 = acc[mt][1][r] + bv[1];
            float v2 = acc[mt][2][r] + bv[2];
            float v3 = acc[mt][3][r] + bv[3];
            float mx = fmaxf(fmaxf(v0, v1), fmaxf(v2, v3));
#pragma unroll
            for (int d = 1; d < 16; d <<= 1) mx = fmaxf(mx, __shfl_xor(mx, d, 64));
            float s = __expf(v0 - mx) + __expf(v1 - mx) + __expf(v2 - mx) + __expf(v3 - mx);
#pragma unroll
            for (int d = 1; d < 16; d <<= 1) s += __shfl_xor(s, d, 64);
            rm[r] = mx; rs[r] = s;
        }
        if ((lane & 15) == 0) {
            int rl = wm * 64 + mt * 16 + (lane >> 4) * 4;
#pragma unroll
            for (int r = 0; r < 4; r++) {
                red_m[wn][rl + r] = rm[r];
                red_s[wn][rl + r] = rs[r];
            }
        }
    }
    __syncthreads();
    if (tid < BM) {
        float m0v = red_m[0][tid], s0v = red_s[0][tid];
        float m1v = red_m[1][tid], s1v = red_s[1][tid];
        float mm = fmaxf(m0v, m1v);
        float ss = s0v * __expf(m0v - mm) + s1v * __expf(m1v - mm);
        long idx = (long)nblk * M_TOK + m0 + tid;
        pm[idx] = mm;
        ps[idx] = ss;
    }
}

// ---------------- combine partials -> per-token logp ----------------
__global__ __launch_bounds__(256) void lse_combine_kernel(const float* __restrict__ pm,
                                                          const float* __restrict__ ps,
                                                          const float* __restrict__ tlogit,
                                                          const int* __restrict__ target,
                                                          float* __restrict__ per_tok) {
    int t = blockIdx.x * blockDim.x + threadIdx.x;
    if (t >= M_TOK) return;
    float m = -1e30f, s = 0.f;
    for (int j = 0; j < NBLK; j++) {
        float mj = pm[j * M_TOK + t];
        float sj = ps[j * M_TOK + t];
        if (mj > m) {
            s = s * expf(m - mj) + sj;
            m = mj;
        } else {
            s += sj * expf(mj - m);
        }
    }
    float lse = m + logf(s);
    int tg = target[t];
    per_tok[t] = (tg != IGNORE_INDEX) ? (tlogit[t] - lse) : 0.0f;
}

// ---------------- final scalar loss ----------------
__global__ __launch_bounds__(512) void final_kernel(const float* __restrict__ per_tok,
                                                    const int* __restrict__ target,
                                                    const float* __restrict__ refc,
                                                    const float* __restrict__ refr,
                                                    float* __restrict__ out) {
    __shared__ float ssum[8];
    __shared__ float scnt[8];
    const int w = threadIdx.x >> 6, lane = threadIdx.x & 63;
    float sum = 0.f, cnt = 0.f;
#pragma unroll
    for (int i = 0; i < 8; i++) {
        int t = w * 512 + i * 64 + lane;
        sum += per_tok[t];
        cnt += (target[t] != IGNORE_INDEX) ? 1.f : 0.f;
    }
#pragma unroll
    for (int d = 1; d < 64; d <<= 1) {
        sum += __shfl_xor(sum, d, 64);
        cnt += __shfl_xor(cnt, d, 64);
    }
    if (lane == 0) { ssum[w] = sum; scnt[w] = cnt; }
    __syncthreads();
    if (threadIdx.x == 0) {
        float avg[8];
#pragma unroll
        for (int i = 0; i < 8; i++) avg[i] = ssum[i] / scnt[i];
        float nll_num = 0.f, nll_den = 0.f;
#pragma unroll
        for (int i = 0; i < 4; i++) { nll_num += ssum[i]; nll_den += scnt[i]; }
        float nll = -nll_num / nll_den;
        float pref = 0.f;
#pragma unroll
        for (int i = 0; i < 4; i++) {
            float x = 0.1f * ((avg[i] - refc[i]) - (avg[i + 4] - refr[i]));
            float ls = (x >= 0.f) ? -log1pf(expf(-x)) : (x - log1pf(expf(x)));
            pref += -ls;
        }
        pref *= 0.25f;
        out[0] = pref + nll;
    }
}

// ---------------- launch ----------------
extern "C" void kernel_launch(void* const* d_in, const int* in_sizes, int n_in,
                              void* d_out, int out_size, void* d_ws, size_t ws_size,
                              hipStream_t stream) {
    const float* W    = (const float*)d_in[0];  // [32000][4096]
    const float* inp  = (const float*)d_in[1];  // [8][512][4096]
    const int*   tgt  = (const int*)d_in[2];    // [8][512]
    const float* refc = (const float*)d_in[3];  // [4]
    const float* refr = (const float*)d_in[4];  // [4]
    const float* bias = (const float*)d_in[5];  // [32000]
    float* out = (float*)d_out;

    char* ws = (char*)d_ws;
    size_t off = 0;
    bf16* A16 = (bf16*)(ws + off); off += (size_t)M_TOK * KH * sizeof(bf16);     // 32 MB
    float* pm = (float*)(ws + off); off += (size_t)NBLK * M_TOK * sizeof(float); // 4 MB
    float* ps = (float*)(ws + off); off += (size_t)NBLK * M_TOK * sizeof(float); // 4 MB
    float* tl = (float*)(ws + off); off += (size_t)M_TOK * sizeof(float);
    float* ptk = (float*)(ws + off); off += (size_t)M_TOK * sizeof(float);
    bf16* W16 = (bf16*)(ws + off);
    size_t need = off + (size_t)NV * KH * sizeof(bf16);                          // +262 MB

    cvt_bf16_kernel<<<4096, 256, 0, stream>>>(inp, A16, (M_TOK * KH) / 4);
    tlogit_kernel<<<M_TOK / 4, 256, 0, stream>>>(inp, W, bias, tgt, tl);
    if (ws_size >= need) {
        cvt_bf16_kernel<<<16384, 256, 0, stream>>>(W, W16, (int)(((size_t)NV * KH) / 4));
        gemm_lse_kernel<true><<<MBLK * NBLK, 256, 0, stream>>>(A16, (const void*)W16, bias, pm, ps);
    } else {
        gemm_lse_kernel<false><<<MBLK * NBLK, 256, 0, stream>>>(A16, (const void*)W, bias, pm, ps);
    }
    lse_combine_kernel<<<(M_TOK + 255) / 256, 256, 0, stream>>>(pm, ps, tl, tgt, ptk);
    final_kernel<<<1, 512, 0, stream>>>(ptk, tgt, refc, refr, out);
}